// Round 7
// baseline (71793.958 us; speedup 1.0000x reference)
//
#include <hip/hip_runtime.h>
#include <hip/hip_bf16.h>
#include <math.h>

#define B_  128
#define T_  256
#define DIN 512
#define H_  1024

typedef __attribute__((ext_vector_type(8))) short bf16x8;
typedef __attribute__((ext_vector_type(4))) float f32x4;

#define GLD_LDS16(gsrc, ldst) \
  __builtin_amdgcn_global_load_lds((const __attribute__((address_space(1))) void*)(gsrc), \
                                   (__attribute__((address_space(3))) void*)(ldst), 16, 0, 0)

__device__ __forceinline__ void split_bf16(float v, __hip_bfloat16* hi, __hip_bfloat16* lo) {
    __hip_bfloat16 h = __float2bfloat16(v);
    *hi = h;
    *lo = __float2bfloat16(v - __bfloat162float(h));
}

__device__ __forceinline__ float sigmoidf_(float x) { return 1.f / (1.f + expf(-x)); }

// --------------------------- small prep kernels ----------------------------
__global__ void bias_sum_k(const float* __restrict__ a, const float* __restrict__ b,
                           float* __restrict__ o, int n) {
    int i = blockIdx.x * blockDim.x + threadIdx.x;
    if (i < n) o[i] = a[i] + b[i];
}

__global__ void detect_mask_k(const int* __restrict__ m, int nwords, int* __restrict__ flag) {
    __shared__ int bad;
    if (threadIdx.x == 0) bad = 0;
    __syncthreads();
    for (int i = threadIdx.x; i < nwords; i += blockDim.x) {
        unsigned v = (unsigned)m[i];
        if (v > 1u) bad = 1;
    }
    __syncthreads();
    if (threadIdx.x == 0) flag[0] = bad ? 0 : 1;  // 1 => int32 mask, 0 => u8 mask
}

__global__ void cvt_split_k(const float* __restrict__ s, __hip_bfloat16* __restrict__ hi,
                            __hip_bfloat16* __restrict__ lo, int n) {
    int i = blockIdx.x * 256 + threadIdx.x;
    if (i < n) split_bf16(s[i], hi + i, lo + i);
}

__global__ void wg_split_k(const float* __restrict__ Wih, const float* __restrict__ Whh,
                           __hip_bfloat16* __restrict__ Wh, __hip_bfloat16* __restrict__ Wl) {
    int i = blockIdx.x * 256 + threadIdx.x;           // over 4096*1536
    int n = i / 1536, c = i - n * 1536;
    float v = (c < DIN) ? Wih[n * DIN + c] : Whh[n * H_ + (c - DIN)];
    split_bf16(v, Wh + i, Wl + i);
}

__device__ __forceinline__ void cvtx_body(int i, const float* __restrict__ xsrc,
                                          __hip_bfloat16* __restrict__ xh,
                                          __hip_bfloat16* __restrict__ xl) {
    int b = i >> 9, c = i & 511;
    split_bf16(xsrc[(size_t)b * (T_ * DIN) + c], xh + i, xl + i);
}

__global__ void cvtx_k(const float* __restrict__ xsrc, __hip_bfloat16* __restrict__ xh,
                       __hip_bfloat16* __restrict__ xl) {
    cvtx_body(blockIdx.x * 256 + threadIdx.x, xsrc, xh, xl);
}

// --------------------------- fused persistent kernel -----------------------
constexpr int APL = 128 * 64 * 2;          // 16 KB per A plane
constexpr int BPL = 32 * 64 * 2;           // 4 KB per B plane
constexpr int BUFB = 2 * APL + 2 * BPL;    // 40 KB
constexpr int LDSZ = 3 * BUFB;             // 120 KB -> 1 block/CU

struct P {
    const float* input; const float* ctx; const void* srcmask;
    const float* bsum; float* cbuf;
    float* gpart; float* qpart; float* opart;
    float* pacc; float* pm; float* ps;
    const int* mflag; unsigned* cnt;
    const __hip_bfloat16 *Wgh, *Wgl, *Wah, *Wal, *Woh, *Wol;
    __hip_bfloat16 *hth, *htl, *AoBh, *AoBl;
    __hip_bfloat16 *xth0, *xtl0, *xth1, *xtl1;
    float* out; float* hf; float* cf;
};

// grid barrier: monotonic per-phase counter, one arrival per block
#define GBAR() do { \
    __syncthreads(); \
    if (tid == 0) { \
        __threadfence(); \
        __hip_atomic_fetch_add(&p.cnt[slot], 1u, __ATOMIC_RELAXED, __HIP_MEMORY_SCOPE_AGENT); \
        while (__hip_atomic_load(&p.cnt[slot], __ATOMIC_RELAXED, __HIP_MEMORY_SCOPE_AGENT) < 256u) \
            __builtin_amdgcn_s_sleep(8); \
        __threadfence(); \
    } \
    ++slot; \
    __syncthreads(); \
  } while (0)

// plane-fused split-bf16 GEMM phase (expanded inline; lds used BY NAME).
// Cpart[KSP][128][32 at NB] = (Ah+Al)@(Wh+Wl)^T slice via 3 MFMA combos.
#define GEMM_PHASE(NT, NB, KSP, A1H, A1L, LDA1, K1V, A2H, A2L, LDA2, WHP, WLP, LDW, CP, LDC, PSTRIDE) \
  { \
    const int n0_ = (NB) * 32; \
    const int kbase_ = (KSP) * ((NT) * 64); \
    const int wm_ = (w >> 1) * 64, wn_ = (w & 1) * 16; \
    auto stage = [&](int buf, int kt) { \
        char* base = lds + buf * BUFB; \
        const int kb = kbase_ + kt * 64; \
        _Pragma("unroll") \
        for (int pp = 0; pp < 2; ++pp) { \
            const __hip_bfloat16* A1 = pp ? (A1L) : (A1H); \
            const __hip_bfloat16* A2 = pp ? (A2L) : (A2H); \
            _Pragma("unroll") \
            for (int j = 0; j < 4; ++j) { \
                int c = j * 256 + tid; \
                int row = c >> 3, sl2 = c & 7; \
                int e = kb + ((sl2 ^ (row & 7)) << 3); \
                const __hip_bfloat16* src = (e < (K1V)) ? (A1 + (long)row * (LDA1) + e) \
                                                        : (A2 + (long)row * (LDA2) + (e - (K1V))); \
                GLD_LDS16(src, base + pp * APL + ((j * 256 + (tid & 192)) << 4)); \
            } \
            { \
                int row = tid >> 3, sl2 = tid & 7; \
                int e = kb + ((sl2 ^ (row & 7)) << 3); \
                const __hip_bfloat16* src = (pp ? (WLP) : (WHP)) + (long)(n0_ + row) * (LDW) + e; \
                GLD_LDS16(src, base + 2 * APL + pp * BPL + ((tid & 192) << 4)); \
            } \
        } \
    }; \
    f32x4 acc[4] = {}; \
    stage(0, 0); \
    if ((NT) > 1) stage(1, 1); \
    for (int kt = 0; kt < (NT); ++kt) { \
        if (kt + 1 < (NT)) asm volatile("s_waitcnt vmcnt(10)" ::: "memory"); \
        else               asm volatile("s_waitcnt vmcnt(0)"  ::: "memory"); \
        __builtin_amdgcn_s_barrier(); \
        __builtin_amdgcn_sched_barrier(0); \
        if (kt + 2 < (NT)) stage((kt + 2) % 3, kt + 2); \
        const char* base = lds + (kt % 3) * BUFB; \
        _Pragma("unroll") \
        for (int ks = 0; ks < 2; ++ks) { \
            bf16x8 afh[4], afl[4], bh, bl; \
            _Pragma("unroll") \
            for (int mi = 0; mi < 4; ++mi) { \
                int row = wm_ + mi * 16 + (l & 15); \
                int sl2 = (l >> 4) + ks * 4; \
                int off = row * 128 + ((sl2 ^ (row & 7)) << 4); \
                afh[mi] = *(const bf16x8*)(base + off); \
                afl[mi] = *(const bf16x8*)(base + APL + off); \
            } \
            { \
                int row = wn_ + (l & 15); \
                int sl2 = (l >> 4) + ks * 4; \
                int off = row * 128 + ((sl2 ^ (row & 7)) << 4); \
                bh = *(const bf16x8*)(base + 2 * APL + off); \
                bl = *(const bf16x8*)(base + 2 * APL + BPL + off); \
            } \
            _Pragma("unroll") \
            for (int mi = 0; mi < 4; ++mi) { \
                acc[mi] = __builtin_amdgcn_mfma_f32_16x16x32_bf16(afh[mi], bh, acc[mi], 0, 0, 0); \
                acc[mi] = __builtin_amdgcn_mfma_f32_16x16x32_bf16(afl[mi], bh, acc[mi], 0, 0, 0); \
                acc[mi] = __builtin_amdgcn_mfma_f32_16x16x32_bf16(afh[mi], bl, acc[mi], 0, 0, 0); \
            } \
        } \
    } \
    float* Cb = (CP) + (long)(KSP) * (PSTRIDE); \
    const int n = n0_ + wn_ + (l & 15); \
    _Pragma("unroll") \
    for (int mi = 0; mi < 4; ++mi) { \
        int mbase = wm_ + mi * 16 + (l >> 4) * 4; \
        _Pragma("unroll") \
        for (int r = 0; r < 4; ++r) \
            Cb[(long)(mbase + r) * (LDC) + n] = acc[mi][r]; \
    } \
  }

__global__ __launch_bounds__(256, 1)
void fused_k(P p)
{
    __shared__ __attribute__((aligned(16))) char lds[LDSZ];
    const int blk = blockIdx.x;      // 0..255
    const int tid = threadIdx.x;
    const int l = tid & 63, w = tid >> 6;
    unsigned slot = 0;

    for (int t = 0; t < T_; ++t) {
        const __hip_bfloat16* xh = (t & 1) ? p.xth1 : p.xth0;
        const __hip_bfloat16* xl = (t & 1) ? p.xtl1 : p.xtl0;

        // ---- G: gates partials  [x_t | h] @ Wg^T   K=1536, Ksplit=2, NT=12
        GEMM_PHASE(12, (blk & 127), (blk >> 7),
                   xh, xl, DIN, DIN,
                   p.hth, p.htl, H_,
                   p.Wgh, p.Wgl, (DIN + H_),
                   p.gpart, (4 * H_), ((long)B_ * 4 * H_));
        GBAR();

        // ---- C: LSTM cell (+bias reduce) + split x_{t+1}
        #pragma unroll
        for (int i = 0; i < 2; ++i) {
            int idx = blk * 512 + i * 256 + tid;
            int b = idx >> 10, j = idx & 1023;
            const float* g0 = p.gpart + ((size_t)b << 12) + j;
            const float* g1 = g0 + (size_t)B_ * 4 * H_;
            float ig = sigmoidf_(g0[0]    + g1[0]    + p.bsum[j]);
            float fg = sigmoidf_(g0[1024] + g1[1024] + p.bsum[1024 + j]);
            float gg = tanhf    (g0[2048] + g1[2048] + p.bsum[2048 + j]);
            float og = sigmoidf_(g0[3072] + g1[3072] + p.bsum[3072 + j]);
            float c = fg * p.cbuf[idx] + ig * gg;
            float h = og * tanhf(c);
            p.cbuf[idx] = c;
            split_bf16(h, p.AoBh + (size_t)b * 2048 + 1024 + j,
                          p.AoBl + (size_t)b * 2048 + 1024 + j);
            if (t == T_ - 1) p.cf[idx] = c;
        }
        if (t + 1 < T_) {
            __hip_bfloat16* nxh = (t & 1) ? p.xth0 : p.xth1;
            __hip_bfloat16* nxl = (t & 1) ? p.xtl0 : p.xtl1;
            cvtx_body(blk * 256 + tid, p.input + (size_t)(t + 1) * DIN, nxh, nxl);
        }
        GBAR();

        // ---- Q: q partials  hy @ Wa^T   K=1024, Ksplit=8, NT=2
        GEMM_PHASE(2, (blk & 31), (blk >> 5),
                   (p.AoBh + H_), (p.AoBl + H_), (2 * H_), (2 * H_),
                   (p.AoBh + H_), (p.AoBl + H_), (2 * H_),
                   p.Wah, p.Wal, H_,
                   p.qpart, H_, ((long)B_ * H_));
        GBAR();

        // ---- A: attention partial over half the L range
        {
            const int b = blk >> 1, half = blk & 1;
            const float* cb = p.ctx + (size_t)b * (T_ * H_);
            const int mode = p.mflag[0];

            float rq[16];
            #pragma unroll
            for (int j = 0; j < 16; ++j) {
                size_t o = (size_t)b * H_ + l + j * 64;
                float s = 0.f;
                #pragma unroll
                for (int ss = 0; ss < 8; ++ss) s += p.qpart[o + (size_t)ss * (B_ * H_)];
                rq[j] = s;
            }

            float m = -INFINITY, s = 0.f, acc[16] = {};
            const int base = half * 128;
            for (int li = base + w; li < base + 128; li += 4) {
                bool msk = mode ? (((const int*)p.srcmask)[b * T_ + li] != 0)
                                : (((const unsigned char*)p.srcmask)[b * T_ + li] != 0);
                if (msk) continue;
                const float* cr = cb + (size_t)li * H_;
                float rc[16], d = 0.f;
                #pragma unroll
                for (int j = 0; j < 16; ++j) { rc[j] = cr[l + j * 64]; d += rc[j] * rq[j]; }
                #pragma unroll
                for (int off = 1; off < 64; off <<= 1) d += __shfl_xor(d, off);
                float mn = fmaxf(m, d);
                float f = expf(m - mn);
                float pp = expf(d - mn);
                s = s * f + pp;
                #pragma unroll
                for (int j = 0; j < 16; ++j) acc[j] = acc[j] * f + pp * rc[j];
                m = mn;
            }

            float (*sacc)[H_] = (float (*)[H_])lds;
            float (*sms)[2]   = (float (*)[2])(lds + 4 * H_ * sizeof(float));
            __syncthreads();
            #pragma unroll
            for (int j = 0; j < 16; ++j) sacc[w][l + j * 64] = acc[j];
            if (l == 0) { sms[w][0] = m; sms[w][1] = s; }
            __syncthreads();

            float M = fmaxf(fmaxf(sms[0][0], sms[1][0]), fmaxf(sms[2][0], sms[3][0]));
            float fw[4], S = 0.f;
            #pragma unroll
            for (int ww = 0; ww < 4; ++ww) {
                fw[ww] = (sms[ww][0] == -INFINITY) ? 0.f : expf(sms[ww][0] - M);
                S += fw[ww] * sms[ww][1];
            }
            int ph = b * 2 + half;
            for (int k = tid; k < H_; k += 256) {
                float a = sacc[0][k] * fw[0] + sacc[1][k] * fw[1] + sacc[2][k] * fw[2] + sacc[3][k] * fw[3];
                p.pacc[(size_t)ph * H_ + k] = a;
            }
            if (tid == 0) { p.pm[ph] = M; p.ps[ph] = S; }
        }
        GBAR();

        // ---- A2: combine halves -> wctx into AoB[:,0:H]
        #pragma unroll
        for (int i = 0; i < 2; ++i) {
            int idx = blk * 512 + i * 256 + tid;
            int b = idx >> 10, k = idx & 1023;
            float m0 = p.pm[2 * b], m1 = p.pm[2 * b + 1];
            float M = fmaxf(m0, m1);
            float f0 = (m0 == -INFINITY) ? 0.f : expf(m0 - M);
            float f1 = (m1 == -INFINITY) ? 0.f : expf(m1 - M);
            float S = f0 * p.ps[2 * b] + f1 * p.ps[2 * b + 1];
            float v = (p.pacc[(size_t)(2 * b) * H_ + k] * f0 +
                       p.pacc[(size_t)(2 * b + 1) * H_ + k] * f1) / S;
            split_bf16(v, p.AoBh + (size_t)b * 2048 + k, p.AoBl + (size_t)b * 2048 + k);
        }
        GBAR();

        // ---- O: out partials  [wctx|hy] @ Wo^T   K=2048, Ksplit=8, NT=4
        GEMM_PHASE(4, (blk & 31), (blk >> 5),
                   p.AoBh, p.AoBl, (2 * H_), (2 * H_),
                   p.AoBh, p.AoBl, (2 * H_),
                   p.Woh, p.Wol, (2 * H_),
                   p.opart, H_, ((long)B_ * H_));
        GBAR();

        // ---- R: reduce + tanh + split -> h_tilde, output slice, (h_f)
        #pragma unroll
        for (int i = 0; i < 2; ++i) {
            int idx = blk * 512 + i * 256 + tid;
            int b = idx >> 10, j = idx & 1023;
            float v = 0.f;
            #pragma unroll
            for (int ss = 0; ss < 8; ++ss) v += p.opart[idx + ss * (B_ * H_)];
            v = tanhf(v);
            split_bf16(v, p.hth + idx, p.htl + idx);
            p.out[(size_t)b * (T_ * H_) + (size_t)t * H_ + j] = v;
            if (t == T_ - 1) p.hf[idx] = v;
        }
        GBAR();
    }
}

// --------------------------- launcher --------------------------------------
extern "C" void kernel_launch(void* const* d_in, const int* in_sizes, int n_in,
                              void* d_out, int out_size, void* d_ws, size_t ws_size,
                              hipStream_t stream)
{
    const float* input  = (const float*)d_in[0];
    const float* h0     = (const float*)d_in[1];
    const float* c0     = (const float*)d_in[2];
    const float* ctx    = (const float*)d_in[3];
    const void*  srcmask= d_in[4];
    const float* W_ih   = (const float*)d_in[5];
    const float* W_hh   = (const float*)d_in[6];
    const float* b_ih   = (const float*)d_in[7];
    const float* b_hh   = (const float*)d_in[8];
    const float* W_attn = (const float*)d_in[9];
    const float* W_out  = (const float*)d_in[10];

    constexpr int B = B_, T = T_, D = DIN, H = H_;

    // -------- workspace --------
    float* f = (float*)d_ws;
    float* bsum  = f; f += 4 * H;
    float* cbuf  = f; f += (size_t)B * H;
    float* gpart = f; f += (size_t)2 * B * 4 * H;
    float* qpart = f; f += (size_t)8 * B * H;
    float* opart = f; f += (size_t)8 * B * H;
    float* pacc  = f; f += (size_t)2 * B * H;
    float* pm    = f; f += 256;
    float* ps    = f; f += 256;
    int*   mflag = (int*)f; f += 64;
    unsigned* cnt = (unsigned*)f; f += 2048;       // 7*256 = 1792 barrier slots
    __hip_bfloat16* p = (__hip_bfloat16*)f;
    __hip_bfloat16* Wgh = p; p += (size_t)4 * H * (D + H);
    __hip_bfloat16* Wgl = p; p += (size_t)4 * H * (D + H);
    __hip_bfloat16* Wah = p; p += (size_t)H * H;
    __hip_bfloat16* Wal = p; p += (size_t)H * H;
    __hip_bfloat16* Woh = p; p += (size_t)H * 2 * H;
    __hip_bfloat16* Wol = p; p += (size_t)H * 2 * H;
    __hip_bfloat16* hth = p; p += (size_t)B * H;
    __hip_bfloat16* htl = p; p += (size_t)B * H;
    __hip_bfloat16* AoBh = p; p += (size_t)B * 2 * H;
    __hip_bfloat16* AoBl = p; p += (size_t)B * 2 * H;
    __hip_bfloat16* xth0 = p; p += (size_t)B * D;
    __hip_bfloat16* xtl0 = p; p += (size_t)B * D;
    __hip_bfloat16* xth1 = p; p += (size_t)B * D;
    __hip_bfloat16* xtl1 = p; p += (size_t)B * D;

    float* out = (float*)d_out;
    float* hf  = out + (size_t)B * T * H;
    float* cf  = hf + (size_t)B * H;

    // -------- prep --------
    hipMemsetAsync(cnt, 0, 2048 * sizeof(unsigned), stream);
    hipMemcpyAsync(cbuf, c0, (size_t)B * H * sizeof(float), hipMemcpyDeviceToDevice, stream);
    bias_sum_k<<<dim3(16), dim3(256), 0, stream>>>(b_ih, b_hh, bsum, 4 * H);
    detect_mask_k<<<dim3(1), dim3(256), 0, stream>>>((const int*)srcmask, B * T / 4, mflag);
    wg_split_k<<<dim3(4 * H * (D + H) / 256), dim3(256), 0, stream>>>(W_ih, W_hh, Wgh, Wgl);
    cvt_split_k<<<dim3(H * H / 256), dim3(256), 0, stream>>>(W_attn, Wah, Wal, H * H);
    cvt_split_k<<<dim3(H * 2 * H / 256), dim3(256), 0, stream>>>(W_out, Woh, Wol, H * 2 * H);
    cvt_split_k<<<dim3(B * H / 256), dim3(256), 0, stream>>>(h0, hth, htl, B * H);
    cvtx_k<<<dim3(B * D / 256), dim3(256), 0, stream>>>(input, xth0, xtl0);

    // -------- persistent fused kernel (1 block/CU via 120KB LDS) --------
    P prm;
    prm.input = input; prm.ctx = ctx; prm.srcmask = srcmask;
    prm.bsum = bsum; prm.cbuf = cbuf;
    prm.gpart = gpart; prm.qpart = qpart; prm.opart = opart;
    prm.pacc = pacc; prm.pm = pm; prm.ps = ps;
    prm.mflag = mflag; prm.cnt = cnt;
    prm.Wgh = Wgh; prm.Wgl = Wgl; prm.Wah = Wah; prm.Wal = Wal;
    prm.Woh = Woh; prm.Wol = Wol;
    prm.hth = hth; prm.htl = htl; prm.AoBh = AoBh; prm.AoBl = AoBl;
    prm.xth0 = xth0; prm.xtl0 = xtl0; prm.xth1 = xth1; prm.xtl1 = xtl1;
    prm.out = out; prm.hf = hf; prm.cf = cf;

    fused_k<<<dim3(256), dim3(256), 0, stream>>>(prm);
}

// Round 8
// 34188.467 us; speedup vs baseline: 2.0999x; 2.0999x over previous
//
#include <hip/hip_runtime.h>
#include <hip/hip_bf16.h>
#include <math.h>

#define B_  128
#define T_  256
#define DIN 512
#define H_  1024

typedef __attribute__((ext_vector_type(8))) short bf16x8;
typedef __attribute__((ext_vector_type(4))) float f32x4;

#define GLD_LDS16(gsrc, ldst) \
  __builtin_amdgcn_global_load_lds((const __attribute__((address_space(1))) void*)(gsrc), \
                                   (__attribute__((address_space(3))) void*)(ldst), 16, 0, 0)

__device__ __forceinline__ void split_bf16(float v, __hip_bfloat16* hi, __hip_bfloat16* lo) {
    __hip_bfloat16 h = __float2bfloat16(v);
    *hi = h;
    *lo = __float2bfloat16(v - __bfloat162float(h));
}

__device__ __forceinline__ float sigmoidf_(float x) { return 1.f / (1.f + expf(-x)); }

// ---- coherent (L2-bypassing, L3-served) access helpers --------------------
__device__ __forceinline__ void cohld1_issue(float* dst, const float* ptr) {
    asm volatile("global_load_dword %0, %1, off sc0 sc1" : "=v"(*dst) : "v"(ptr));
}
__device__ __forceinline__ void cohst1(float* ptr, float v) {
    asm volatile("global_store_dword %0, %1, off sc0 sc1" :: "v"(ptr), "v"(v) : "memory");
}
__device__ __forceinline__ void cohst_u16(unsigned short* ptr, unsigned int v) {
    asm volatile("global_store_short %0, %1, off sc0 sc1" :: "v"(ptr), "v"(v) : "memory");
}
__device__ __forceinline__ void cohst_split(unsigned short* hip_, unsigned short* lop_, float v) {
    __hip_bfloat16 h, lo2;
    split_bf16(v, &h, &lo2);
    cohst_u16(hip_, *(unsigned short*)&h);
    cohst_u16(lop_, *(unsigned short*)&lo2);
}
#define COH_WAIT() do { asm volatile("s_waitcnt vmcnt(0)" ::: "memory"); \
                        __builtin_amdgcn_sched_barrier(0); } while (0)

// --------------------------- small prep kernels ----------------------------
__global__ void bias_sum_k(const float* __restrict__ a, const float* __restrict__ b,
                           float* __restrict__ o, int n) {
    int i = blockIdx.x * blockDim.x + threadIdx.x;
    if (i < n) o[i] = a[i] + b[i];
}

__global__ void detect_mask_k(const int* __restrict__ m, int nwords, int* __restrict__ flag) {
    __shared__ int bad;
    if (threadIdx.x == 0) bad = 0;
    __syncthreads();
    for (int i = threadIdx.x; i < nwords; i += blockDim.x) {
        unsigned v = (unsigned)m[i];
        if (v > 1u) bad = 1;
    }
    __syncthreads();
    if (threadIdx.x == 0) flag[0] = bad ? 0 : 1;  // 1 => int32 mask, 0 => u8 mask
}

__global__ void cvt_split_k(const float* __restrict__ s, __hip_bfloat16* __restrict__ hi,
                            __hip_bfloat16* __restrict__ lo, int n) {
    int i = blockIdx.x * 256 + threadIdx.x;
    if (i < n) split_bf16(s[i], hi + i, lo + i);
}

__global__ void wg_split_k(const float* __restrict__ Wih, const float* __restrict__ Whh,
                           __hip_bfloat16* __restrict__ Wh, __hip_bfloat16* __restrict__ Wl) {
    int i = blockIdx.x * 256 + threadIdx.x;           // over 4096*1536
    int n = i / 1536, c = i - n * 1536;
    float v = (c < DIN) ? Wih[n * DIN + c] : Whh[n * H_ + (c - DIN)];
    split_bf16(v, Wh + i, Wl + i);
}

__global__ void cvtx_k(const float* __restrict__ xsrc, __hip_bfloat16* __restrict__ xh,
                       __hip_bfloat16* __restrict__ xl) {
    int i = blockIdx.x * 256 + threadIdx.x;
    int b = i >> 9, c = i & 511;
    split_bf16(xsrc[(size_t)b * (T_ * DIN) + c], xh + i, xl + i);
}

// --------------------------- fused persistent kernel -----------------------
constexpr int APL = 128 * 64 * 2;          // 16 KB per A plane
constexpr int BPL = 32 * 64 * 2;           // 4 KB per B plane
constexpr int BUFB = 2 * APL + 2 * BPL;    // 40 KB
constexpr int LDSZ = 3 * BUFB;             // 120 KB -> 1 block/CU

struct P {
    const float* input; const float* ctx; const void* srcmask;
    const float* bsum; float* cbuf;
    float* gpart; float* qpart; float* opart;
    float* pacc; float* pm; float* ps;
    const int* mflag; unsigned* cnt;
    const __hip_bfloat16 *Wgh, *Wgl, *Wah, *Wal, *Woh, *Wol;
    unsigned short *hth, *htl, *AoBh, *AoBl;
    unsigned short *xth0, *xtl0, *xth1, *xtl1;
    float* out; float* hf; float* cf;
};

// grid barrier: NO cache maintenance (all shared data goes through sc0/sc1
// coherent path; __syncthreads drains vmcnt). Relaxed agent atomics only.
#define GBAR() do { \
    __syncthreads(); \
    if (tid == 0) { \
        __hip_atomic_fetch_add(&p.cnt[slot], 1u, __ATOMIC_RELAXED, __HIP_MEMORY_SCOPE_AGENT); \
        while (__hip_atomic_load(&p.cnt[slot], __ATOMIC_RELAXED, __HIP_MEMORY_SCOPE_AGENT) < 256u) \
            __builtin_amdgcn_s_sleep(8); \
    } \
    ++slot; \
    __syncthreads(); \
  } while (0)

// ---- GEMM building blocks (file-scope macros; use locals set by GEMM_PHASE)
#define GP_ISSUE_A(KT) { \
    const int kbi_ = kbase_ + (KT) * 64; \
    _Pragma("unroll") \
    for (int pp = 0; pp < 2; ++pp) { \
        const unsigned short* A1p_ = pp ? A1l_ : A1h_; \
        const unsigned short* A2p_ = pp ? A2l_ : A2h_; \
        _Pragma("unroll") \
        for (int j = 0; j < 4; ++j) { \
            int c_ = j * 256 + tid; \
            int row_ = c_ >> 3, sl_ = c_ & 7; \
            int e_ = kbi_ + ((sl_ ^ (row_ & 7)) << 3); \
            const unsigned short* src_ = (e_ < K1_) ? (A1p_ + (long)row_ * lda1_ + e_) \
                                                    : (A2p_ + (long)row_ * lda2_ + (e_ - K1_)); \
            asm volatile("global_load_dwordx4 %0, %1, off sc0 sc1" \
                         : "=v"(rA[pp][j]) : "v"(src_)); \
        } \
    } }

#define GP_WRITE_A(BUF) { \
    char* wb_ = lds + (BUF) * BUFB; \
    _Pragma("unroll") \
    for (int pp = 0; pp < 2; ++pp) \
        _Pragma("unroll") \
        for (int j = 0; j < 4; ++j) \
            *(uint4*)(wb_ + pp * APL + (j * 256 + tid) * 16) = rA[pp][j]; \
    }

#define GP_ISSUE_B(KT, BUF) { \
    char* bb_ = lds + (BUF) * BUFB; \
    const int kbi_ = kbase_ + (KT) * 64; \
    int row_ = tid >> 3, sl_ = tid & 7; \
    int e_ = kbi_ + ((sl_ ^ (row_ & 7)) << 3); \
    _Pragma("unroll") \
    for (int pp = 0; pp < 2; ++pp) { \
        const __hip_bfloat16* src_ = (pp ? Wl_ : Wh_) + (long)(n0_ + row_) * ldw_ + e_; \
        GLD_LDS16(src_, bb_ + 2 * APL + pp * BPL + ((tid & 192) << 4)); \
    } }

// plane-fused split-bf16 GEMM phase: Cpart[KSP][128][32 at NB] via 3 MFMA
// combos (hh, lh, hl). A-state staged via coherent asm loads -> ds_write
// (3-buffer, 1-tile-ahead); B (weights) via cached global_load_lds.
#define GEMM_PHASE(NT, NB, KSP, A1H, A1L, LDA1, K1V, A2H, A2L, LDA2, WHP, WLP, LDW, CP, LDC, PSTRIDE) \
  { \
    const int n0_ = (NB) * 32; \
    const int kbase_ = (KSP) * ((NT) * 64); \
    const int wm_ = (w >> 1) * 64, wn_ = (w & 1) * 16; \
    const unsigned short* A1h_ = (const unsigned short*)(A1H); \
    const unsigned short* A1l_ = (const unsigned short*)(A1L); \
    const unsigned short* A2h_ = (const unsigned short*)(A2H); \
    const unsigned short* A2l_ = (const unsigned short*)(A2L); \
    const long lda1_ = (LDA1), lda2_ = (LDA2), ldw_ = (LDW); \
    const int K1_ = (K1V); \
    const __hip_bfloat16* Wh_ = (WHP); \
    const __hip_bfloat16* Wl_ = (WLP); \
    uint4 rA[2][4]; \
    f32x4 acc[4] = {}; \
    GP_ISSUE_A(0); \
    GP_ISSUE_B(0, 0); \
    asm volatile("s_waitcnt vmcnt(2)" ::: "memory"); \
    __builtin_amdgcn_sched_barrier(0); \
    GP_WRITE_A(0); \
    GP_ISSUE_A(1); \
    GP_ISSUE_B(1, 1); \
    for (int kt = 0; kt < (NT); ++kt) { \
        asm volatile("s_waitcnt vmcnt(0) lgkmcnt(0)" ::: "memory"); \
        __builtin_amdgcn_s_barrier(); \
        __builtin_amdgcn_sched_barrier(0); \
        if (kt + 1 < (NT)) GP_WRITE_A((kt + 1) % 3); \
        if (kt + 2 < (NT)) { GP_ISSUE_A(kt + 2); GP_ISSUE_B(kt + 2, (kt + 2) % 3); } \
        const char* base = lds + (kt % 3) * BUFB; \
        _Pragma("unroll") \
        for (int ks = 0; ks < 2; ++ks) { \
            bf16x8 afh[4], afl[4], bh, bl; \
            _Pragma("unroll") \
            for (int mi = 0; mi < 4; ++mi) { \
                int row = wm_ + mi * 16 + (l & 15); \
                int sl2 = (l >> 4) + ks * 4; \
                int off = row * 128 + ((sl2 ^ (row & 7)) << 4); \
                afh[mi] = *(const bf16x8*)(base + off); \
                afl[mi] = *(const bf16x8*)(base + APL + off); \
            } \
            { \
                int row = wn_ + (l & 15); \
                int sl2 = (l >> 4) + ks * 4; \
                int off = row * 128 + ((sl2 ^ (row & 7)) << 4); \
                bh = *(const bf16x8*)(base + 2 * APL + off); \
                bl = *(const bf16x8*)(base + 2 * APL + BPL + off); \
            } \
            _Pragma("unroll") \
            for (int mi = 0; mi < 4; ++mi) { \
                acc[mi] = __builtin_amdgcn_mfma_f32_16x16x32_bf16(afh[mi], bh, acc[mi], 0, 0, 0); \
                acc[mi] = __builtin_amdgcn_mfma_f32_16x16x32_bf16(afl[mi], bh, acc[mi], 0, 0, 0); \
                acc[mi] = __builtin_amdgcn_mfma_f32_16x16x32_bf16(afh[mi], bl, acc[mi], 0, 0, 0); \
            } \
        } \
    } \
    float* Cb = (CP) + (long)(KSP) * (PSTRIDE); \
    const int n = n0_ + wn_ + (l & 15); \
    _Pragma("unroll") \
    for (int mi = 0; mi < 4; ++mi) { \
        int mbase = wm_ + mi * 16 + (l >> 4) * 4; \
        _Pragma("unroll") \
        for (int r = 0; r < 4; ++r) \
            cohst1(Cb + (long)(mbase + r) * (LDC) + n, acc[mi][r]); \
    } \
  }

__global__ __launch_bounds__(256, 1)
void fused_k(P p)
{
    __shared__ __attribute__((aligned(16))) char lds[LDSZ];
    const int blk = blockIdx.x;      // 0..255
    const int tid = threadIdx.x;
    const int l = tid & 63, w = tid >> 6;
    unsigned slot = 0;

    for (int t = 0; t < T_; ++t) {
        const unsigned short* xh = (t & 1) ? p.xth1 : p.xth0;
        const unsigned short* xl = (t & 1) ? p.xtl1 : p.xtl0;

        // ---- G: gates partials  [x_t | h] @ Wg^T   K=1536, Ksplit=2, NT=12
        GEMM_PHASE(12, (blk & 127), (blk >> 7),
                   xh, xl, DIN, DIN,
                   p.hth, p.htl, H_,
                   p.Wgh, p.Wgl, (DIN + H_),
                   p.gpart, (4 * H_), ((long)B_ * 4 * H_));
        GBAR();

        // ---- C: LSTM cell (+bias reduce) + split x_{t+1}
        {
            float gv[16];
            int idxA[2];
            #pragma unroll
            for (int i = 0; i < 2; ++i) {
                int idx = blk * 512 + i * 256 + tid;
                idxA[i] = idx;
                int b = idx >> 10, j = idx & 1023;
                const float* g0 = p.gpart + ((long)b << 12) + j;
                const float* g1 = g0 + (long)B_ * 4 * H_;
                cohld1_issue(&gv[i * 8 + 0], g0);
                cohld1_issue(&gv[i * 8 + 1], g0 + 1024);
                cohld1_issue(&gv[i * 8 + 2], g0 + 2048);
                cohld1_issue(&gv[i * 8 + 3], g0 + 3072);
                cohld1_issue(&gv[i * 8 + 4], g1);
                cohld1_issue(&gv[i * 8 + 5], g1 + 1024);
                cohld1_issue(&gv[i * 8 + 6], g1 + 2048);
                cohld1_issue(&gv[i * 8 + 7], g1 + 3072);
            }
            COH_WAIT();
            #pragma unroll
            for (int i = 0; i < 2; ++i) {
                int idx = idxA[i];
                int b = idx >> 10, j = idx & 1023;
                float ig = sigmoidf_(gv[i * 8 + 0] + gv[i * 8 + 4] + p.bsum[j]);
                float fg = sigmoidf_(gv[i * 8 + 1] + gv[i * 8 + 5] + p.bsum[1024 + j]);
                float gg = tanhf    (gv[i * 8 + 2] + gv[i * 8 + 6] + p.bsum[2048 + j]);
                float og = sigmoidf_(gv[i * 8 + 3] + gv[i * 8 + 7] + p.bsum[3072 + j]);
                float c = fg * p.cbuf[idx] + ig * gg;
                float h = og * tanhf(c);
                p.cbuf[idx] = c;
                cohst_split(p.AoBh + (long)b * 2048 + 1024 + j,
                            p.AoBl + (long)b * 2048 + 1024 + j, h);
                if (t == T_ - 1) p.cf[idx] = c;
            }
            if (t + 1 < T_) {
                unsigned short* nxh = (t & 1) ? p.xth0 : p.xth1;
                unsigned short* nxl = (t & 1) ? p.xtl0 : p.xtl1;
                int i = blk * 256 + tid;
                int b = i >> 9, c = i & 511;
                float xv = p.input[(long)b * (T_ * DIN) + (long)(t + 1) * DIN + c];
                cohst_split(nxh + i, nxl + i, xv);
            }
        }
        GBAR();

        // ---- Q: q partials  hy @ Wa^T   K=1024, Ksplit=4, NT=4 (128 blocks)
        if (blk < 128) {
            GEMM_PHASE(4, (blk & 31), (blk >> 5),
                       (p.AoBh + H_), (p.AoBl + H_), (2 * H_), (2 * H_),
                       (p.AoBh + H_), (p.AoBl + H_), (2 * H_),
                       p.Wah, p.Wal, H_,
                       p.qpart, H_, ((long)B_ * H_));
        }
        GBAR();

        // ---- A: attention partial over half the L range
        {
            const int b = blk >> 1, half = blk & 1;
            const float* cb = p.ctx + (long)b * (T_ * H_);
            const int mode = p.mflag[0];

            float qt[64];
            #pragma unroll
            for (int j = 0; j < 16; ++j) {
                const float* qp = p.qpart + (long)b * H_ + l + j * 64;
                #pragma unroll
                for (int ss = 0; ss < 4; ++ss)
                    cohld1_issue(&qt[j * 4 + ss], qp + (long)ss * (B_ * H_));
            }
            COH_WAIT();
            float rq[16];
            #pragma unroll
            for (int j = 0; j < 16; ++j)
                rq[j] = (qt[j * 4] + qt[j * 4 + 1]) + (qt[j * 4 + 2] + qt[j * 4 + 3]);

            float m = -INFINITY, s = 0.f, acc[16] = {};
            const int base = half * 128;
            for (int li = base + w; li < base + 128; li += 4) {
                bool msk = mode ? (((const int*)p.srcmask)[b * T_ + li] != 0)
                                : (((const unsigned char*)p.srcmask)[b * T_ + li] != 0);
                if (msk) continue;
                const float* cr = cb + (long)li * H_;
                float rc[16], d = 0.f;
                #pragma unroll
                for (int j = 0; j < 16; ++j) { rc[j] = cr[l + j * 64]; d += rc[j] * rq[j]; }
                #pragma unroll
                for (int off = 1; off < 64; off <<= 1) d += __shfl_xor(d, off);
                float mn = fmaxf(m, d);
                float f = expf(m - mn);
                float pp = expf(d - mn);
                s = s * f + pp;
                #pragma unroll
                for (int j = 0; j < 16; ++j) acc[j] = acc[j] * f + pp * rc[j];
                m = mn;
            }

            float (*sacc)[H_] = (float (*)[H_])lds;
            float (*sms)[2]   = (float (*)[2])(lds + 4 * H_ * sizeof(float));
            __syncthreads();
            #pragma unroll
            for (int j = 0; j < 16; ++j) sacc[w][l + j * 64] = acc[j];
            if (l == 0) { sms[w][0] = m; sms[w][1] = s; }
            __syncthreads();

            float M = fmaxf(fmaxf(sms[0][0], sms[1][0]), fmaxf(sms[2][0], sms[3][0]));
            float fw[4], S = 0.f;
            #pragma unroll
            for (int ww = 0; ww < 4; ++ww) {
                fw[ww] = (sms[ww][0] == -INFINITY) ? 0.f : expf(sms[ww][0] - M);
                S += fw[ww] * sms[ww][1];
            }
            int ph = b * 2 + half;
            for (int k = tid; k < H_; k += 256) {
                float a = sacc[0][k] * fw[0] + sacc[1][k] * fw[1] + sacc[2][k] * fw[2] + sacc[3][k] * fw[3];
                cohst1(p.pacc + (long)ph * H_ + k, a);
            }
            if (tid == 0) { cohst1(p.pm + ph, M); cohst1(p.ps + ph, S); }
        }
        GBAR();

        // ---- A2: combine halves -> wctx into AoB[:,0:H]
        {
            float av[12];
            int idxA[2];
            #pragma unroll
            for (int i = 0; i < 2; ++i) {
                int idx = blk * 512 + i * 256 + tid;
                idxA[i] = idx;
                int b = idx >> 10, k = idx & 1023;
                cohld1_issue(&av[i * 6 + 0], p.pacc + (long)(2 * b) * H_ + k);
                cohld1_issue(&av[i * 6 + 1], p.pacc + (long)(2 * b + 1) * H_ + k);
                cohld1_issue(&av[i * 6 + 2], p.pm + 2 * b);
                cohld1_issue(&av[i * 6 + 3], p.pm + 2 * b + 1);
                cohld1_issue(&av[i * 6 + 4], p.ps + 2 * b);
                cohld1_issue(&av[i * 6 + 5], p.ps + 2 * b + 1);
            }
            COH_WAIT();
            #pragma unroll
            for (int i = 0; i < 2; ++i) {
                int idx = idxA[i];
                int b = idx >> 10, k = idx & 1023;
                float m0 = av[i * 6 + 2], m1 = av[i * 6 + 3];
                float M = fmaxf(m0, m1);
                float f0 = (m0 == -INFINITY) ? 0.f : expf(m0 - M);
                float f1 = (m1 == -INFINITY) ? 0.f : expf(m1 - M);
                float S = f0 * av[i * 6 + 4] + f1 * av[i * 6 + 5];
                float v = (av[i * 6 + 0] * f0 + av[i * 6 + 1] * f1) / S;
                cohst_split(p.AoBh + (long)b * 2048 + k, p.AoBl + (long)b * 2048 + k, v);
            }
        }
        GBAR();

        // ---- O: out partials  [wctx|hy] @ Wo^T   K=2048, Ksplit=8, NT=4
        GEMM_PHASE(4, (blk & 31), (blk >> 5),
                   p.AoBh, p.AoBl, (2 * H_), (2 * H_),
                   p.AoBh, p.AoBl, (2 * H_),
                   p.Woh, p.Wol, (2 * H_),
                   p.opart, H_, ((long)B_ * H_));
        GBAR();

        // ---- R: reduce + tanh + split -> h_tilde, output slice, (h_f)
        {
            float ov[16];
            int idxA[2];
            #pragma unroll
            for (int i = 0; i < 2; ++i) {
                int idx = blk * 512 + i * 256 + tid;
                idxA[i] = idx;
                #pragma unroll
                for (int ss = 0; ss < 8; ++ss)
                    cohld1_issue(&ov[i * 8 + ss], p.opart + idx + (long)ss * (B_ * H_));
            }
            COH_WAIT();
            #pragma unroll
            for (int i = 0; i < 2; ++i) {
                int idx = idxA[i];
                int b = idx >> 10, j = idx & 1023;
                float v = 0.f;
                #pragma unroll
                for (int ss = 0; ss < 8; ++ss) v += ov[i * 8 + ss];
                v = tanhf(v);
                cohst_split(p.hth + idx, p.htl + idx, v);
                p.out[(long)b * (T_ * H_) + (long)t * H_ + j] = v;
                if (t == T_ - 1) p.hf[idx] = v;
            }
        }
        GBAR();
    }
}

// --------------------------- launcher --------------------------------------
extern "C" void kernel_launch(void* const* d_in, const int* in_sizes, int n_in,
                              void* d_out, int out_size, void* d_ws, size_t ws_size,
                              hipStream_t stream)
{
    const float* input  = (const float*)d_in[0];
    const float* h0     = (const float*)d_in[1];
    const float* c0     = (const float*)d_in[2];
    const float* ctx    = (const float*)d_in[3];
    const void*  srcmask= d_in[4];
    const float* W_ih   = (const float*)d_in[5];
    const float* W_hh   = (const float*)d_in[6];
    const float* b_ih   = (const float*)d_in[7];
    const float* b_hh   = (const float*)d_in[8];
    const float* W_attn = (const float*)d_in[9];
    const float* W_out  = (const float*)d_in[10];

    constexpr int B = B_, T = T_, D = DIN, H = H_;

    // -------- workspace --------
    float* f = (float*)d_ws;
    float* bsum  = f; f += 4 * H;
    float* cbuf  = f; f += (size_t)B * H;
    float* gpart = f; f += (size_t)2 * B * 4 * H;
    float* qpart = f; f += (size_t)8 * B * H;
    float* opart = f; f += (size_t)8 * B * H;
    float* pacc  = f; f += (size_t)2 * B * H;
    float* pm    = f; f += 256;
    float* ps    = f; f += 256;
    int*   mflag = (int*)f; f += 64;
    unsigned* cnt = (unsigned*)f; f += 2048;       // 7*256 = 1792 barrier slots
    __hip_bfloat16* p = (__hip_bfloat16*)f;
    __hip_bfloat16* Wgh = p; p += (size_t)4 * H * (D + H);
    __hip_bfloat16* Wgl = p; p += (size_t)4 * H * (D + H);
    __hip_bfloat16* Wah = p; p += (size_t)H * H;
    __hip_bfloat16* Wal = p; p += (size_t)H * H;
    __hip_bfloat16* Woh = p; p += (size_t)H * 2 * H;
    __hip_bfloat16* Wol = p; p += (size_t)H * 2 * H;
    __hip_bfloat16* hth = p; p += (size_t)B * H;
    __hip_bfloat16* htl = p; p += (size_t)B * H;
    __hip_bfloat16* AoBh = p; p += (size_t)B * 2 * H;
    __hip_bfloat16* AoBl = p; p += (size_t)B * 2 * H;
    __hip_bfloat16* xth0 = p; p += (size_t)B * D;
    __hip_bfloat16* xtl0 = p; p += (size_t)B * D;
    __hip_bfloat16* xth1 = p; p += (size_t)B * D;
    __hip_bfloat16* xtl1 = p; p += (size_t)B * D;

    float* out = (float*)d_out;
    float* hf  = out + (size_t)B * T * H;
    float* cf  = hf + (size_t)B * H;

    // -------- prep --------
    hipMemsetAsync(cnt, 0, 2048 * sizeof(unsigned), stream);
    hipMemcpyAsync(cbuf, c0, (size_t)B * H * sizeof(float), hipMemcpyDeviceToDevice, stream);
    bias_sum_k<<<dim3(16), dim3(256), 0, stream>>>(b_ih, b_hh, bsum, 4 * H);
    detect_mask_k<<<dim3(1), dim3(256), 0, stream>>>((const int*)srcmask, B * T / 4, mflag);
    wg_split_k<<<dim3(4 * H * (D + H) / 256), dim3(256), 0, stream>>>(W_ih, W_hh, Wgh, Wgl);
    cvt_split_k<<<dim3(H * H / 256), dim3(256), 0, stream>>>(W_attn, Wah, Wal, H * H);
    cvt_split_k<<<dim3(H * 2 * H / 256), dim3(256), 0, stream>>>(W_out, Woh, Wol, H * 2 * H);
    cvt_split_k<<<dim3(B * H / 256), dim3(256), 0, stream>>>(h0, hth, htl, B * H);
    cvtx_k<<<dim3(B * D / 256), dim3(256), 0, stream>>>(input, xth0, xtl0);

    // -------- persistent fused kernel (1 block/CU via 120KB LDS) --------
    P prm;
    prm.input = input; prm.ctx = ctx; prm.srcmask = srcmask;
    prm.bsum = bsum; prm.cbuf = cbuf;
    prm.gpart = gpart; prm.qpart = qpart; prm.opart = opart;
    prm.pacc = pacc; prm.pm = pm; prm.ps = ps;
    prm.mflag = mflag; prm.cnt = cnt;
    prm.Wgh = Wgh; prm.Wgl = Wgl; prm.Wah = Wah; prm.Wal = Wal;
    prm.Woh = Woh; prm.Wol = Wol;
    prm.hth = (unsigned short*)hth; prm.htl = (unsigned short*)htl;
    prm.AoBh = (unsigned short*)AoBh; prm.AoBl = (unsigned short*)AoBl;
    prm.xth0 = (unsigned short*)xth0; prm.xtl0 = (unsigned short*)xtl0;
    prm.xth1 = (unsigned short*)xth1; prm.xtl1 = (unsigned short*)xtl1;
    prm.out = out; prm.hf = hf; prm.cf = cf;

    fused_k<<<dim3(256), dim3(256), 0, stream>>>(prm);
}